// Round 18
// baseline (695.809 us; speedup 1.0000x reference)
//
#include <hip/hip_runtime.h>
#include <stdint.h>

static constexpr int NU    = 100000;
static constexpr int NI    = 200000;
static constexpr int D     = 64;
static constexpr int E_UI  = 3200000;
static constexpr int E_SOC = 1600000;
static constexpr int CH    = 8192;   // edges per binning block
static constexpr int BROWS = 512;    // rows per bucket
#define EPS_LN 1e-5f

typedef __attribute__((ext_vector_type(8))) short bf16x8;
typedef __attribute__((ext_vector_type(4))) float f32x4;

__device__ __forceinline__ unsigned short f2b(float f) {
    unsigned u = __float_as_uint(f);
    u = (u + 0x7FFFu + ((u >> 16) & 1u)) >> 16;   // RNE
    return (unsigned short)u;
}
__device__ __forceinline__ float b2fs(unsigned short h) {
    return __uint_as_float((unsigned)h << 16);
}
__device__ __forceinline__ float b2f_lo(unsigned u) { return __uint_as_float(u << 16); }
__device__ __forceinline__ float b2f_hi(unsigned u) { return __uint_as_float(u & 0xFFFF0000u); }

__device__ __forceinline__ void fma8(float* a, float w, uint4 h) {
    a[0] += w * b2f_lo(h.x); a[1] += w * b2f_hi(h.x);
    a[2] += w * b2f_lo(h.y); a[3] += w * b2f_hi(h.y);
    a[4] += w * b2f_lo(h.z); a[5] += w * b2f_hi(h.z);
    a[6] += w * b2f_lo(h.w); a[7] += w * b2f_hi(h.w);
}

// ================= CSR build structs =================
struct CntT { const int* rows; int E; int nblk; int nb; int* cnt; int blk0; };
struct ScanT { const int* cnt; int n; int* bsum; int* ofs; int blk0; };
struct ScatT { const int* rows; const int* idxs; const float* vals;
               int E; int nblk; const int* ofs; int nb; int2* binned; int blk0; };
struct FineT { const int2* binned; const int* ofs; int nblk; int nb;
               int E; int nrows; int* rowptr; int2* rec; int blk0; };

// ---------- table GEMM task ----------
struct TaskT {
    const float* x;
    unsigned short* tab;
    const float* W;
    int ntiles;
    int blk0;
    int nblk;
    float* cpyA;   // optional fp32 copy of x (e.g. ui_list[0])
    float* cpyB;   // optional second copy (e.g. soc_list[0])
};

__device__ __forceinline__ void split_hi_lo(const f32x4 a, const f32x4 b,
                                            bf16x8& hi, bf16x8& lo)
{
    #pragma unroll
    for (int j = 0; j < 4; ++j) {
        unsigned short h = f2b(a[j]);
        hi[j] = (short)h;
        lo[j] = (short)f2b(a[j] - b2fs(h));
    }
    #pragma unroll
    for (int j = 0; j < 4; ++j) {
        unsigned short h = f2b(b[j]);
        hi[4 + j] = (short)h;
        lo[4 + j] = (short)f2b(b[j] - b2fs(h));
    }
}

__device__ __forceinline__ void btab_device(const TaskT& t, float* Wl, int bidx)
{
    {
        const float4* W4 = (const float4*)t.W;
        float4* Wl4 = (float4*)Wl;
        for (int i = threadIdx.x; i < 1024; i += 256) Wl4[i] = W4[i];
    }
    __syncthreads();

    int wv   = threadIdx.x >> 6;
    int lane = threadIdx.x & 63;
    int g    = lane >> 4;
    int c    = lane & 15;

    bf16x8 Whi[2][4], Wlo[2][4];
    #pragma unroll
    for (int kt = 0; kt < 2; ++kt)
        #pragma unroll
        for (int nt = 0; nt < 4; ++nt)
            #pragma unroll
            for (int j = 0; j < 8; ++j) {
                float w = Wl[(kt * 32 + 8 * g + j) * 64 + nt * 16 + c];
                unsigned short h = f2b(w);
                Whi[kt][nt][j] = (short)h;
                Wlo[kt][nt][j] = (short)f2b(w - b2fs(h));
            }

    int stride = t.nblk * 4;
    for (int tile = (bidx - t.blk0) * 4 + wv; tile < t.ntiles; tile += stride) {
        int rowbase = tile * 16;
        const float* arow = t.x + (size_t)(rowbase + c) * 64 + 8 * g;
        f32x4 a00 = *(const f32x4*)(arow);
        f32x4 a01 = *(const f32x4*)(arow + 4);
        f32x4 a10 = *(const f32x4*)(arow + 32);
        f32x4 a11 = *(const f32x4*)(arow + 36);
        if (t.cpyA) {   // fold copy0: store loaded x to both layer-0 output slabs
            float* dA = t.cpyA + (size_t)(rowbase + c) * 64 + 8 * g;
            *(f32x4*)(dA)      = a00; *(f32x4*)(dA + 4)  = a01;
            *(f32x4*)(dA + 32) = a10; *(f32x4*)(dA + 36) = a11;
            float* dB = t.cpyB + (size_t)(rowbase + c) * 64 + 8 * g;
            *(f32x4*)(dB)      = a00; *(f32x4*)(dB + 4)  = a01;
            *(f32x4*)(dB + 32) = a10; *(f32x4*)(dB + 36) = a11;
        }
        bf16x8 Ahi0, Alo0, Ahi1, Alo1;
        split_hi_lo(a00, a01, Ahi0, Alo0);
        split_hi_lo(a10, a11, Ahi1, Alo1);

        #pragma unroll
        for (int nt = 0; nt < 4; ++nt) {
            f32x4 z = {0.f, 0.f, 0.f, 0.f};
            z = __builtin_amdgcn_mfma_f32_16x16x32_bf16(Ahi0, Whi[0][nt], z, 0, 0, 0);
            z = __builtin_amdgcn_mfma_f32_16x16x32_bf16(Ahi1, Whi[1][nt], z, 0, 0, 0);
            z = __builtin_amdgcn_mfma_f32_16x16x32_bf16(Alo0, Whi[0][nt], z, 0, 0, 0);
            z = __builtin_amdgcn_mfma_f32_16x16x32_bf16(Alo1, Whi[1][nt], z, 0, 0, 0);
            z = __builtin_amdgcn_mfma_f32_16x16x32_bf16(Ahi0, Wlo[0][nt], z, 0, 0, 0);
            z = __builtin_amdgcn_mfma_f32_16x16x32_bf16(Ahi1, Wlo[1][nt], z, 0, 0, 0);
            #pragma unroll
            for (int reg = 0; reg < 4; ++reg)
                t.tab[(size_t)(rowbase + 4 * g + reg) * 64 + nt * 16 + c] = f2b(z[reg]);
        }
    }
}

// ---------- front dispatch: bin_count3 (CSR phase 1) ∥ btab3(L0) ----------
__global__ void __launch_bounds__(256) front_l0(CntT c1, CntT c2, CntT c3, int nCnt,
                                                TaskT ta, TaskT tb, TaskT tc)
{
    __shared__ float Wl[64 * 64];   // btab W tile; first 512 ints reused as hist
    if ((int)blockIdx.x < nCnt) {
        int* hist = (int*)Wl;
        CntT c = ((int)blockIdx.x >= c3.blk0) ? c3
               : ((int)blockIdx.x >= c2.blk0) ? c2 : c1;
        int b = blockIdx.x - c.blk0, t = threadIdx.x;
        for (int i = t; i < c.nb; i += 256) hist[i] = 0;
        __syncthreads();
        int e0 = b * CH, e1 = min(c.E, e0 + CH);
        for (int e = e0 + t; e < e1; e += 256)
            atomicAdd(&hist[c.rows[e] >> 9], 1);
        __syncthreads();
        for (int i = t; i < c.nb; i += 256) c.cnt[i * c.nblk + b] = hist[i];
    } else {
        int bidx = blockIdx.x - nCnt;
        const TaskT& t = (bidx >= tc.blk0) ? tc : (bidx >= tb.blk0) ? tb : ta;
        btab_device(t, Wl, bidx);
    }
}

// plain btab (layer 1)
__global__ void __launch_bounds__(256) btab3(TaskT t0, TaskT t1, TaskT t2)
{
    __shared__ float Wl[64 * 64];
    const TaskT& t = ((int)blockIdx.x >= t2.blk0) ? t2
                   : ((int)blockIdx.x >= t1.blk0) ? t1 : t0;
    btab_device(t, Wl, blockIdx.x);
}

// ---------- scans ----------
__global__ void scan_partial3(ScanT s0, ScanT s1, ScanT s2)
{
    __shared__ int lds[256];
    ScanT s = (blockIdx.x >= (unsigned)s2.blk0) ? s2
            : (blockIdx.x >= (unsigned)s1.blk0) ? s1 : s0;
    int bb = blockIdx.x - s.blk0;
    int i = bb * 256 + threadIdx.x;
    lds[threadIdx.x] = (i < s.n) ? s.cnt[i] : 0;
    __syncthreads();
    for (int off = 128; off > 0; off >>= 1) {
        if (threadIdx.x < off) lds[threadIdx.x] += lds[threadIdx.x + off];
        __syncthreads();
    }
    if (threadIdx.x == 0) s.bsum[bb] = lds[0];
}

__global__ void scan_bsums3(ScanT s0, ScanT s1, ScanT s2)
{
    __shared__ int lds[1024];
    ScanT s = (blockIdx.x == 2) ? s2 : (blockIdx.x == 1) ? s1 : s0;
    int nb = (s.n + 255) / 256;
    int t = threadIdx.x;
    int v = (t < nb) ? s.bsum[t] : 0;
    lds[t] = v;
    __syncthreads();
    for (int off = 1; off < 1024; off <<= 1) {
        int add = (t >= off) ? lds[t - off] : 0;
        __syncthreads();
        lds[t] += add;
        __syncthreads();
    }
    if (t < nb) s.bsum[t] = lds[t] - v;
}

__global__ void scan_out3(ScanT s0, ScanT s1, ScanT s2)
{
    __shared__ int lds[256];
    ScanT s = (blockIdx.x >= (unsigned)s2.blk0) ? s2
            : (blockIdx.x >= (unsigned)s1.blk0) ? s1 : s0;
    int bb = blockIdx.x - s.blk0;
    int i = bb * 256 + threadIdx.x;
    int v = (i < s.n) ? s.cnt[i] : 0;
    lds[threadIdx.x] = v;
    __syncthreads();
    for (int off = 1; off < 256; off <<= 1) {
        int add = (threadIdx.x >= off) ? lds[threadIdx.x - off] : 0;
        __syncthreads();
        lds[threadIdx.x] += add;
        __syncthreads();
    }
    if (i < s.n) s.ofs[i] = s.bsum[bb] + lds[threadIdx.x] - v;
}

__global__ void __launch_bounds__(256) bin_scatter3(ScatT c0, ScatT c1, ScatT c2)
{
    __shared__ int cur[512];
    ScatT c = (blockIdx.x >= (unsigned)c2.blk0) ? c2
            : (blockIdx.x >= (unsigned)c1.blk0) ? c1 : c0;
    int b = blockIdx.x - c.blk0, t = threadIdx.x;
    for (int i = t; i < c.nb; i += 256) cur[i] = c.ofs[i * c.nblk + b];
    __syncthreads();
    int e0 = b * CH, e1 = min(c.E, e0 + CH);
    for (int e = e0 + t; e < e1; e += 256) {
        int row = c.rows[e];
        int bucket = row >> 9;
        int slot = atomicAdd(&cur[bucket], 1);
        unsigned pack = ((unsigned)(row & 511) << 23) | (unsigned)c.idxs[e];
        c.binned[slot] = make_int2((int)pack, __float_as_int(c.vals[e]));
    }
}

__global__ void __launch_bounds__(512) fine_scatter3(FineT c0, FineT c1, FineT c2)
{
    __shared__ int hist[512];
    __shared__ int cur[512];
    FineT c = (blockIdx.x >= (unsigned)c2.blk0) ? c2
            : (blockIdx.x >= (unsigned)c1.blk0) ? c1 : c0;
    int b = blockIdx.x - c.blk0, t = threadIdx.x;
    int beg = c.ofs[b * c.nblk];
    int end = (b + 1 < c.nb) ? c.ofs[(b + 1) * c.nblk] : c.E;

    hist[t] = 0;
    __syncthreads();
    for (int j = beg + t; j < end; j += 512)
        atomicAdd(&hist[((unsigned)c.binned[j].x) >> 23], 1);
    __syncthreads();
    int v = hist[t];
    for (int off = 1; off < 512; off <<= 1) {
        int add = (t >= off) ? hist[t - off] : 0;
        __syncthreads();
        hist[t] += add;
        __syncthreads();
    }
    int excl = hist[t] - v;
    cur[t] = excl;
    int grow = b * BROWS + t;
    if (grow <= c.nrows) c.rowptr[grow] = beg + excl;
    __syncthreads();
    for (int j = beg + t; j < end; j += 512) {
        int2 eb = c.binned[j];
        unsigned p = (unsigned)eb.x;
        int rl  = (int)(p >> 23);
        int idx = (int)(p & 0x7FFFFFu);
        int cc = atomicAdd(&cur[rl], 1);
        c.rec[beg + cc] = make_int2(idx, eb.y);
    }
}

// ---------- fused SpMM(pre-transformed table) + bias + residual + LN ----------
// 2 rows per wave (32 lanes/row): 4 edge-groups x 8 lanes x 16B; 4-deep batch.
struct TaskS {
    const unsigned short* gsrc;
    const float* xin;
    float* yout;
    const int* rowptr;
    const int2* recs;
    const float* bias;
    const float* gamma;
    const float* beta;
    int nrows;
    int blk0;
};

__global__ void __launch_bounds__(256) spmmln3(TaskS t0, TaskS t1, TaskS t2)
{
    TaskS t = (blockIdx.x >= (unsigned)t2.blk0) ? t2
            : (blockIdx.x >= (unsigned)t1.blk0) ? t1 : t0;
    int wid2 = (blockIdx.x - t.blk0) * 4 + (threadIdx.x >> 6);   // wave index
    int lane = threadIdx.x & 63;
    int half = lane >> 5;          // row within wave
    int row  = wid2 * 2 + half;
    if (row >= t.nrows) return;    // nrows even -> whole waves exit

    int g4 = (lane >> 3) & 3;      // edge sub-group 0..3 (within 32-lane half)
    int l8 = lane & 7;             // ushort8 slot (dims 8*l8 .. 8*l8+7)

    float accA[8], accB[8];
    #pragma unroll
    for (int m = 0; m < 8; ++m) { accA[m] = 0.f; accB[m] = 0.f; }

    int beg = t.rowptr[row], end = t.rowptr[row + 1];
    int jb = beg;
    for (; jb + 16 <= end; jb += 16) {
        int2 r0 = t.recs[jb + g4];
        int2 r1 = t.recs[jb + 4 + g4];
        int2 r2 = t.recs[jb + 8 + g4];
        int2 r3 = t.recs[jb + 12 + g4];
        uint4 h0 = ((const uint4*)(t.gsrc + (size_t)r0.x * 64))[l8];
        uint4 h1 = ((const uint4*)(t.gsrc + (size_t)r1.x * 64))[l8];
        uint4 h2 = ((const uint4*)(t.gsrc + (size_t)r2.x * 64))[l8];
        uint4 h3 = ((const uint4*)(t.gsrc + (size_t)r3.x * 64))[l8];
        fma8(accA, __int_as_float(r0.y), h0);
        fma8(accB, __int_as_float(r1.y), h1);
        fma8(accA, __int_as_float(r2.y), h2);
        fma8(accB, __int_as_float(r3.y), h3);
    }
    if (jb < end) {
        int endm1 = end - 1;       // >= jb >= 0 here
        int e0 = jb + g4, e1 = jb + 4 + g4, e2 = jb + 8 + g4, e3 = jb + 12 + g4;
        int2 r0 = t.recs[min(e0, endm1)];
        int2 r1 = t.recs[min(e1, endm1)];
        int2 r2 = t.recs[min(e2, endm1)];
        int2 r3 = t.recs[min(e3, endm1)];
        if (e0 < end) { uint4 h = ((const uint4*)(t.gsrc + (size_t)r0.x * 64))[l8]; fma8(accA, __int_as_float(r0.y), h); }
        if (e1 < end) { uint4 h = ((const uint4*)(t.gsrc + (size_t)r1.x * 64))[l8]; fma8(accB, __int_as_float(r1.y), h); }
        if (e2 < end) { uint4 h = ((const uint4*)(t.gsrc + (size_t)r2.x * 64))[l8]; fma8(accA, __int_as_float(r2.y), h); }
        if (e3 < end) { uint4 h = ((const uint4*)(t.gsrc + (size_t)r3.x * 64))[l8]; fma8(accB, __int_as_float(r3.y), h); }
    }
    float acc[8];
    #pragma unroll
    for (int m = 0; m < 8; ++m) acc[m] = accA[m] + accB[m];
    #pragma unroll
    for (int off = 8; off <= 16; off <<= 1)
        #pragma unroll
        for (int m = 0; m < 8; ++m)
            acc[m] += __shfl_xor(acc[m], off);

    // residual + bias + LayerNorm
    const float4* xi = (const float4*)(t.xin + (size_t)row * 64 + 8 * l8);
    const float4* bi = (const float4*)(t.bias + 8 * l8);
    float4 x0 = xi[0], x1 = xi[1];
    float4 bb0 = bi[0], bb1 = bi[1];
    float tv[8];
    tv[0] = x0.x + acc[0] + bb0.x; tv[1] = x0.y + acc[1] + bb0.y;
    tv[2] = x0.z + acc[2] + bb0.z; tv[3] = x0.w + acc[3] + bb0.w;
    tv[4] = x1.x + acc[4] + bb1.x; tv[5] = x1.y + acc[5] + bb1.y;
    tv[6] = x1.z + acc[6] + bb1.z; tv[7] = x1.w + acc[7] + bb1.w;

    float s = 0.f;
    #pragma unroll
    for (int m = 0; m < 8; ++m) s += tv[m];
    #pragma unroll
    for (int off = 1; off <= 4; off <<= 1) s += __shfl_xor(s, off);
    float mean = s * (1.0f / 64.0f);
    float q = 0.f;
    #pragma unroll
    for (int m = 0; m < 8; ++m) { float dv = tv[m] - mean; q += dv * dv; }
    #pragma unroll
    for (int off = 1; off <= 4; off <<= 1) q += __shfl_xor(q, off);
    float rs = rsqrtf(q * (1.0f / 64.0f) + EPS_LN);

    if (g4 == 0) {
        const float4* ga = (const float4*)(t.gamma + 8 * l8);
        const float4* be = (const float4*)(t.beta + 8 * l8);
        float4 g0 = ga[0], g1 = ga[1];
        float4 e0 = be[0], e1 = be[1];
        float4 y0, y1;
        y0.x = (tv[0] - mean) * rs * g0.x + e0.x;
        y0.y = (tv[1] - mean) * rs * g0.y + e0.y;
        y0.z = (tv[2] - mean) * rs * g0.z + e0.z;
        y0.w = (tv[3] - mean) * rs * g0.w + e0.w;
        y1.x = (tv[4] - mean) * rs * g1.x + e1.x;
        y1.y = (tv[5] - mean) * rs * g1.y + e1.y;
        y1.z = (tv[6] - mean) * rs * g1.z + e1.z;
        y1.w = (tv[7] - mean) * rs * g1.w + e1.w;
        float4* yo = (float4*)(t.yout + (size_t)row * 64 + 8 * l8);
        yo[0] = y0;
        yo[1] = y1;
    }
}

extern "C" void kernel_launch(void* const* d_in, const int* in_sizes, int n_in,
                              void* d_out, int out_size, void* d_ws, size_t ws_size,
                              hipStream_t stream)
{
    const float* user_emb = (const float*)d_in[0];
    const float* item_emb = (const float*)d_in[1];
    const int*   ui_src   = (const int*)d_in[2];
    const int*   ui_dst   = (const int*)d_in[3];
    const float* ui_val   = (const float*)d_in[4];
    const int*   soc_src  = (const int*)d_in[5];
    const int*   soc_dst  = (const int*)d_in[6];
    const float* soc_val  = (const float*)d_in[7];
    const float* W_ui     = (const float*)d_in[8];
    const float* b_ui     = (const float*)d_in[9];
    const float* W_soc    = (const float*)d_in[10];
    const float* b_soc    = (const float*)d_in[11];
    const float* ln_g     = (const float*)d_in[12];
    const float* ln_b     = (const float*)d_in[13];

    float* out     = (float*)d_out;
    float* out_ui  = out;                         // [3][NU][D]
    float* out_soc = out + (size_t)3 * NU * D;    // [3][NU][D]
    float* out_it  = out + (size_t)6 * NU * D;    // [NI][D]

    const int NBU = (NU + BROWS - 1) / BROWS;     // 196
    const int NBI = (NI + BROWS - 1) / BROWS;     // 391
    const int BLK_UI  = (E_UI  + CH - 1) / CH;    // 391
    const int BLK_SOC = (E_SOC + CH - 1) / CH;    // 196

    const int N1 = NBU * BLK_UI;    // 76636
    const int N2 = NBI * BLK_UI;    // 152881
    const int N3 = NBU * BLK_SOC;   // 38416
    const int SB1 = (N1 + 255) / 256, SB2 = (N2 + 255) / 256, SB3 = (N3 + 255) / 256;

    // ---- workspace carve (256B-aligned) ----
    char* p = (char*)d_ws;
    auto take = [&](size_t bytes) { char* r = p; p += (bytes + 255) & ~(size_t)255; return r; };
    int2* rec_us = (int2*)take((size_t)E_UI * 8);
    int2* rec_ud = (int2*)take((size_t)E_UI * 8);
    int2* rec_ss = (int2*)take((size_t)E_SOC * 8);
    int2* bin1 = (int2*)take((size_t)E_UI * 8);
    int2* bin2 = (int2*)take((size_t)E_UI * 8);
    int2* bin3 = (int2*)take((size_t)E_SOC * 8);
    int*  rp_us  = (int*)take((size_t)(NU + 1) * 4);
    int*  rp_ud  = (int*)take((size_t)(NI + 1) * 4);
    int*  rp_ss  = (int*)take((size_t)(NU + 1) * 4);
    int*  cnt1 = (int*)take((size_t)N1 * 4);
    int*  cnt2 = (int*)take((size_t)N2 * 4);
    int*  cnt3 = (int*)take((size_t)N3 * 4);
    int*  ofs1 = (int*)take((size_t)N1 * 4);
    int*  ofs2 = (int*)take((size_t)N2 * 4);
    int*  ofs3 = (int*)take((size_t)N3 * 4);
    int*  bs1 = (int*)take(1024 * 4);
    int*  bs2 = (int*)take(1024 * 4);
    int*  bs3 = (int*)take(1024 * 4);
    unsigned short* twi = (unsigned short*)take((size_t)NU * D * 2);  // u_cur @ W_ui
    unsigned short* tws = (unsigned short*)take((size_t)NU * D * 2);  // s_cur @ W_soc
    unsigned short* twu = (unsigned short*)take((size_t)NI * D * 2);  // it_cur @ W_ui (own buffer now)

    const int TB_I = 1040, TB_U = 520, TB_S = 520;
    int tgrid = TB_I + TB_U + TB_S;
    const int TIL_I = NI / 16, TIL_U = NU / 16;   // 12500, 6250

    const float* u0 = user_emb;
    float* u1 = out_ui + (size_t)NU * D;
    float* u2 = out_ui + (size_t)2 * NU * D;
    const float* s0 = user_emb;
    float* s1 = out_soc + (size_t)NU * D;
    float* s2 = out_soc + (size_t)2 * NU * D;

    // ---- front dispatch: bin_count3 (phase 1) ∥ btab3(L0) (+copy0 folded) ----
    int nCnt = 2 * BLK_UI + BLK_SOC;   // 978
    {
        CntT c1 { ui_src,  E_UI,  BLK_UI,  NBU, cnt1, 0 };
        CntT c2 { ui_dst,  E_UI,  BLK_UI,  NBI, cnt2, BLK_UI };
        CntT c3 { soc_src, E_SOC, BLK_SOC, NBU, cnt3, 2 * BLK_UI };
        TaskT ta { item_emb, twu, W_ui + 0 * 4096, TIL_I, 0, TB_I, nullptr, nullptr };
        TaskT tb { u0,       twi, W_ui + 0 * 4096, TIL_U, TB_I, TB_U, out_ui, out_soc };
        TaskT tc { u0,       tws, W_soc + 0 * 4096, TIL_U, TB_I + TB_U, TB_S, nullptr, nullptr };
        front_l0<<<nCnt + tgrid, 256, 0, stream>>>(c1, c2, c3, nCnt, ta, tb, tc);
    }
    {
        ScanT s1s { cnt1, N1, bs1, ofs1, 0 };
        ScanT s2s { cnt2, N2, bs2, ofs2, SB1 };
        ScanT s3s { cnt3, N3, bs3, ofs3, SB1 + SB2 };
        scan_partial3<<<SB1 + SB2 + SB3, 256, 0, stream>>>(s1s, s2s, s3s);
        scan_bsums3<<<3, 1024, 0, stream>>>(s1s, s2s, s3s);
        scan_out3<<<SB1 + SB2 + SB3, 256, 0, stream>>>(s1s, s2s, s3s);
    }
    {
        ScatT c1 { ui_src,  ui_dst,  ui_val,  E_UI,  BLK_UI,  ofs1, NBU, bin1, 0 };
        ScatT c2 { ui_dst,  ui_src,  ui_val,  E_UI,  BLK_UI,  ofs2, NBI, bin2, BLK_UI };
        ScatT c3 { soc_src, soc_dst, soc_val, E_SOC, BLK_SOC, ofs3, NBU, bin3, 2 * BLK_UI };
        bin_scatter3<<<2 * BLK_UI + BLK_SOC, 256, 0, stream>>>(c1, c2, c3);
    }
    {
        FineT f1 { bin1, ofs1, BLK_UI,  NBU, E_UI,  NU, rp_us, rec_us, 0 };
        FineT f2 { bin2, ofs2, BLK_UI,  NBI, E_UI,  NI, rp_ud, rec_ud, NBU };
        FineT f3 { bin3, ofs3, BLK_SOC, NBU, E_SOC, NU, rp_ss, rec_ss, NBU + NBI };
        fine_scatter3<<<NBU + NBI + NBU, 512, 0, stream>>>(f1, f2, f3);
    }

    int ublocks8 = (NU + 7) / 8;   // 12500
    int iblocks8 = (NI + 7) / 8;   // 25000
    int agrid    = iblocks8 + 2 * ublocks8;

    // ---- layer 0 spmm+LN ----
    {
        TaskS si { twi, item_emb, out_it, rp_ud, rec_ud, b_ui + 0 * 64,
                   ln_g + 1 * 64, ln_b + 1 * 64, NI, 0 };
        TaskS su { twu, u0, u1, rp_us, rec_us, b_ui + 0 * 64,
                   ln_g + 0 * 64, ln_b + 0 * 64, NU, iblocks8 };
        TaskS ss { tws, s0, s1, rp_ss, rec_ss, b_soc + 0 * 64,
                   ln_g + 0 * 64, ln_b + 0 * 64, NU, iblocks8 + ublocks8 };
        spmmln3<<<agrid, 256, 0, stream>>>(si, su, ss);
    }

    // ---- layer 1 ----
    {
        TaskT ta { out_it, twu, W_ui + 1 * 4096, TIL_I, 0, TB_I, nullptr, nullptr };
        TaskT tb { u1,     twi, W_ui + 1 * 4096, TIL_U, TB_I, TB_U, nullptr, nullptr };
        TaskT tc { s1,     tws, W_soc + 1 * 4096, TIL_U, TB_I + TB_U, TB_S, nullptr, nullptr };
        btab3<<<tgrid, 256, 0, stream>>>(ta, tb, tc);
    }
    {
        TaskS si { twi, out_it, out_it, rp_ud, rec_ud, b_ui + 1 * 64,
                   ln_g + 3 * 64, ln_b + 3 * 64, NI, 0 };
        TaskS su { twu, u1, u2, rp_us, rec_us, b_ui + 1 * 64,
                   ln_g + 2 * 64, ln_b + 2 * 64, NU, iblocks8 };
        TaskS ss { tws, s1, s2, rp_ss, rec_ss, b_soc + 1 * 64,
                   ln_g + 2 * 64, ln_b + 2 * 64, NU, iblocks8 + ublocks8 };
        spmmln3<<<agrid, 256, 0, stream>>>(si, su, ss);
    }
}

// Round 21
// 685.670 us; speedup vs baseline: 1.0148x; 1.0148x over previous
//
#include <hip/hip_runtime.h>
#include <stdint.h>

static constexpr int NU    = 100000;
static constexpr int NI    = 200000;
static constexpr int D     = 64;
static constexpr int E_UI  = 3200000;
static constexpr int E_SOC = 1600000;
static constexpr int CH    = 8192;   // edges per binning block
static constexpr int BROWS = 512;    // rows per bucket
#define EPS_LN 1e-5f

typedef __attribute__((ext_vector_type(8))) short bf16x8;
typedef __attribute__((ext_vector_type(4))) float f32x4;

__device__ __forceinline__ unsigned short f2b(float f) {
    unsigned u = __float_as_uint(f);
    u = (u + 0x7FFFu + ((u >> 16) & 1u)) >> 16;   // RNE
    return (unsigned short)u;
}
__device__ __forceinline__ float b2fs(unsigned short h) {
    return __uint_as_float((unsigned)h << 16);
}
__device__ __forceinline__ float b2f_lo(unsigned u) { return __uint_as_float(u << 16); }
__device__ __forceinline__ float b2f_hi(unsigned u) { return __uint_as_float(u & 0xFFFF0000u); }

__device__ __forceinline__ void fma8(float* a, float w, uint4 h) {
    a[0] += w * b2f_lo(h.x); a[1] += w * b2f_hi(h.x);
    a[2] += w * b2f_lo(h.y); a[3] += w * b2f_hi(h.y);
    a[4] += w * b2f_lo(h.z); a[5] += w * b2f_hi(h.z);
    a[6] += w * b2f_lo(h.w); a[7] += w * b2f_hi(h.w);
}

// ================= CSR build: 3 graphs merged per phase =================
struct CntT { const int* rows; int E; int nblk; int nb; int* cnt; int blk0; };

__global__ void __launch_bounds__(256) bin_count3(CntT c0, CntT c1, CntT c2)
{
    __shared__ int hist[512];
    CntT c = (blockIdx.x >= (unsigned)c2.blk0) ? c2
           : (blockIdx.x >= (unsigned)c1.blk0) ? c1 : c0;
    int b = blockIdx.x - c.blk0, t = threadIdx.x;
    for (int i = t; i < c.nb; i += 256) hist[i] = 0;
    __syncthreads();
    int e0 = b * CH, e1 = min(c.E, e0 + CH);
    for (int e = e0 + t; e < e1; e += 256)
        atomicAdd(&hist[c.rows[e] >> 9], 1);
    __syncthreads();
    for (int i = t; i < c.nb; i += 256) c.cnt[i * c.nblk + b] = hist[i];
}

struct ScanT { const int* cnt; int n; int* bsum; int* ofs; int blk0; };

__global__ void scan_partial3(ScanT s0, ScanT s1, ScanT s2)
{
    __shared__ int lds[256];
    ScanT s = (blockIdx.x >= (unsigned)s2.blk0) ? s2
            : (blockIdx.x >= (unsigned)s1.blk0) ? s1 : s0;
    int bb = blockIdx.x - s.blk0;
    int i = bb * 256 + threadIdx.x;
    lds[threadIdx.x] = (i < s.n) ? s.cnt[i] : 0;
    __syncthreads();
    for (int off = 128; off > 0; off >>= 1) {
        if (threadIdx.x < off) lds[threadIdx.x] += lds[threadIdx.x + off];
        __syncthreads();
    }
    if (threadIdx.x == 0) s.bsum[bb] = lds[0];
}

__global__ void scan_bsums3(ScanT s0, ScanT s1, ScanT s2)
{
    __shared__ int lds[1024];
    ScanT s = (blockIdx.x == 2) ? s2 : (blockIdx.x == 1) ? s1 : s0;
    int nb = (s.n + 255) / 256;
    int t = threadIdx.x;
    int v = (t < nb) ? s.bsum[t] : 0;
    lds[t] = v;
    __syncthreads();
    for (int off = 1; off < 1024; off <<= 1) {
        int add = (t >= off) ? lds[t - off] : 0;
        __syncthreads();
        lds[t] += add;
        __syncthreads();
    }
    if (t < nb) s.bsum[t] = lds[t] - v;
}

__global__ void scan_out3(ScanT s0, ScanT s1, ScanT s2)
{
    __shared__ int lds[256];
    ScanT s = (blockIdx.x >= (unsigned)s2.blk0) ? s2
            : (blockIdx.x >= (unsigned)s1.blk0) ? s1 : s0;
    int bb = blockIdx.x - s.blk0;
    int i = bb * 256 + threadIdx.x;
    int v = (i < s.n) ? s.cnt[i] : 0;
    lds[threadIdx.x] = v;
    __syncthreads();
    for (int off = 1; off < 256; off <<= 1) {
        int add = (threadIdx.x >= off) ? lds[threadIdx.x - off] : 0;
        __syncthreads();
        lds[threadIdx.x] += add;
        __syncthreads();
    }
    if (i < s.n) s.ofs[i] = s.bsum[bb] + lds[threadIdx.x] - v;
}

struct ScatT { const int* rows; const int* idxs; const float* vals;
               int E; int nblk; const int* ofs; int nb; int2* binned; int blk0; };

__global__ void __launch_bounds__(256) bin_scatter3(ScatT c0, ScatT c1, ScatT c2)
{
    __shared__ int cur[512];
    ScatT c = (blockIdx.x >= (unsigned)c2.blk0) ? c2
            : (blockIdx.x >= (unsigned)c1.blk0) ? c1 : c0;
    int b = blockIdx.x - c.blk0, t = threadIdx.x;
    for (int i = t; i < c.nb; i += 256) cur[i] = c.ofs[i * c.nblk + b];
    __syncthreads();
    int e0 = b * CH, e1 = min(c.E, e0 + CH);
    for (int e = e0 + t; e < e1; e += 256) {
        int row = c.rows[e];
        int bucket = row >> 9;
        int slot = atomicAdd(&cur[bucket], 1);
        unsigned pack = ((unsigned)(row & 511) << 23) | (unsigned)c.idxs[e];
        c.binned[slot] = make_int2((int)pack, __float_as_int(c.vals[e]));
    }
}

struct FineT { const int2* binned; const int* ofs; int nblk; int nb;
               int E; int nrows; int* rowptr; int2* rec; int blk0; };

__global__ void __launch_bounds__(512) fine_scatter3(FineT c0, FineT c1, FineT c2)
{
    __shared__ int hist[512];
    __shared__ int cur[512];
    FineT c = (blockIdx.x >= (unsigned)c2.blk0) ? c2
            : (blockIdx.x >= (unsigned)c1.blk0) ? c1 : c0;
    int b = blockIdx.x - c.blk0, t = threadIdx.x;
    int beg = c.ofs[b * c.nblk];
    int end = (b + 1 < c.nb) ? c.ofs[(b + 1) * c.nblk] : c.E;

    hist[t] = 0;
    __syncthreads();
    for (int j = beg + t; j < end; j += 512)
        atomicAdd(&hist[((unsigned)c.binned[j].x) >> 23], 1);
    __syncthreads();
    int v = hist[t];
    for (int off = 1; off < 512; off <<= 1) {
        int add = (t >= off) ? hist[t - off] : 0;
        __syncthreads();
        hist[t] += add;
        __syncthreads();
    }
    int excl = hist[t] - v;
    cur[t] = excl;
    int grow = b * BROWS + t;
    if (grow <= c.nrows) c.rowptr[grow] = beg + excl;
    __syncthreads();
    for (int j = beg + t; j < end; j += 512) {
        int2 eb = c.binned[j];
        unsigned p = (unsigned)eb.x;
        int rl  = (int)(p >> 23);
        int idx = (int)(p & 0x7FFFFFu);
        int cc = atomicAdd(&cur[rl], 1);
        c.rec[beg + cc] = make_int2(idx, eb.y);
    }
}

// ---------- table GEMM: tab = bf16(X @ W), MFMA hi/lo split ----------
struct TaskT {
    const float* x;
    unsigned short* tab;
    const float* W;
    int ntiles;
    int blk0;
    int nblk;
    float* cpyA;   // optional fp32 copy of x (ui_list[0])
    float* cpyB;   // optional second copy (soc_list[0])
};

__device__ __forceinline__ void split_hi_lo(const f32x4 a, const f32x4 b,
                                            bf16x8& hi, bf16x8& lo)
{
    #pragma unroll
    for (int j = 0; j < 4; ++j) {
        unsigned short h = f2b(a[j]);
        hi[j] = (short)h;
        lo[j] = (short)f2b(a[j] - b2fs(h));
    }
    #pragma unroll
    for (int j = 0; j < 4; ++j) {
        unsigned short h = f2b(b[j]);
        hi[4 + j] = (short)h;
        lo[4 + j] = (short)f2b(b[j] - b2fs(h));
    }
}

__global__ void __launch_bounds__(256) btab3(TaskT t0, TaskT t1, TaskT t2)
{
    __shared__ float Wl[64 * 64];
    const TaskT& t = ((int)blockIdx.x >= t2.blk0) ? t2
                   : ((int)blockIdx.x >= t1.blk0) ? t1 : t0;
    {
        const float4* W4 = (const float4*)t.W;
        float4* Wl4 = (float4*)Wl;
        for (int i = threadIdx.x; i < 1024; i += 256) Wl4[i] = W4[i];
    }
    __syncthreads();

    int wv   = threadIdx.x >> 6;
    int lane = threadIdx.x & 63;
    int g    = lane >> 4;
    int c    = lane & 15;

    bf16x8 Whi[2][4], Wlo[2][4];
    #pragma unroll
    for (int kt = 0; kt < 2; ++kt)
        #pragma unroll
        for (int nt = 0; nt < 4; ++nt)
            #pragma unroll
            for (int j = 0; j < 8; ++j) {
                float w = Wl[(kt * 32 + 8 * g + j) * 64 + nt * 16 + c];
                unsigned short h = f2b(w);
                Whi[kt][nt][j] = (short)h;
                Wlo[kt][nt][j] = (short)f2b(w - b2fs(h));
            }

    int stride = t.nblk * 4;
    for (int tile = ((int)blockIdx.x - t.blk0) * 4 + wv; tile < t.ntiles; tile += stride) {
        int rowbase = tile * 16;
        const float* arow = t.x + (size_t)(rowbase + c) * 64 + 8 * g;
        f32x4 a00 = *(const f32x4*)(arow);
        f32x4 a01 = *(const f32x4*)(arow + 4);
        f32x4 a10 = *(const f32x4*)(arow + 32);
        f32x4 a11 = *(const f32x4*)(arow + 36);
        if (t.cpyA) {   // fold copy0: store loaded x to both layer-0 output slabs
            float* dA = t.cpyA + (size_t)(rowbase + c) * 64 + 8 * g;
            *(f32x4*)(dA)      = a00; *(f32x4*)(dA + 4)  = a01;
            *(f32x4*)(dA + 32) = a10; *(f32x4*)(dA + 36) = a11;
            float* dB = t.cpyB + (size_t)(rowbase + c) * 64 + 8 * g;
            *(f32x4*)(dB)      = a00; *(f32x4*)(dB + 4)  = a01;
            *(f32x4*)(dB + 32) = a10; *(f32x4*)(dB + 36) = a11;
        }
        bf16x8 Ahi0, Alo0, Ahi1, Alo1;
        split_hi_lo(a00, a01, Ahi0, Alo0);
        split_hi_lo(a10, a11, Ahi1, Alo1);

        #pragma unroll
        for (int nt = 0; nt < 4; ++nt) {
            f32x4 z = {0.f, 0.f, 0.f, 0.f};
            z = __builtin_amdgcn_mfma_f32_16x16x32_bf16(Ahi0, Whi[0][nt], z, 0, 0, 0);
            z = __builtin_amdgcn_mfma_f32_16x16x32_bf16(Ahi1, Whi[1][nt], z, 0, 0, 0);
            z = __builtin_amdgcn_mfma_f32_16x16x32_bf16(Alo0, Whi[0][nt], z, 0, 0, 0);
            z = __builtin_amdgcn_mfma_f32_16x16x32_bf16(Alo1, Whi[1][nt], z, 0, 0, 0);
            z = __builtin_amdgcn_mfma_f32_16x16x32_bf16(Ahi0, Wlo[0][nt], z, 0, 0, 0);
            z = __builtin_amdgcn_mfma_f32_16x16x32_bf16(Ahi1, Wlo[1][nt], z, 0, 0, 0);
            #pragma unroll
            for (int reg = 0; reg < 4; ++reg)
                t.tab[(size_t)(rowbase + 4 * g + reg) * 64 + nt * 16 + c] = f2b(z[reg]);
        }
    }
}

// ---------- fused SpMM(pre-transformed table) + bias + residual + LN ----------
// 2 rows per wave (32 lanes/row): 4 edge-groups x 8 lanes x 16B; 4-deep batch.
struct TaskS {
    const unsigned short* gsrc;
    const float* xin;
    float* yout;
    const int* rowptr;
    const int2* recs;
    const float* bias;
    const float* gamma;
    const float* beta;
    int nrows;
    int blk0;
};

__global__ void __launch_bounds__(256) spmmln3(TaskS t0, TaskS t1, TaskS t2)
{
    TaskS t = (blockIdx.x >= (unsigned)t2.blk0) ? t2
            : (blockIdx.x >= (unsigned)t1.blk0) ? t1 : t0;
    int wid2 = (blockIdx.x - t.blk0) * 4 + (threadIdx.x >> 6);   // wave index
    int lane = threadIdx.x & 63;
    int half = lane >> 5;          // row within wave
    int row  = wid2 * 2 + half;
    if (row >= t.nrows) return;    // nrows even -> whole waves exit

    int g4 = (lane >> 3) & 3;      // edge sub-group 0..3 (within 32-lane half)
    int l8 = lane & 7;             // ushort8 slot (dims 8*l8 .. 8*l8+7)

    float accA[8], accB[8];
    #pragma unroll
    for (int m = 0; m < 8; ++m) { accA[m] = 0.f; accB[m] = 0.f; }

    int beg = t.rowptr[row], end = t.rowptr[row + 1];
    int jb = beg;
    for (; jb + 16 <= end; jb += 16) {
        int2 r0 = t.recs[jb + g4];
        int2 r1 = t.recs[jb + 4 + g4];
        int2 r2 = t.recs[jb + 8 + g4];
        int2 r3 = t.recs[jb + 12 + g4];
        uint4 h0 = ((const uint4*)(t.gsrc + (size_t)r0.x * 64))[l8];
        uint4 h1 = ((const uint4*)(t.gsrc + (size_t)r1.x * 64))[l8];
        uint4 h2 = ((const uint4*)(t.gsrc + (size_t)r2.x * 64))[l8];
        uint4 h3 = ((const uint4*)(t.gsrc + (size_t)r3.x * 64))[l8];
        fma8(accA, __int_as_float(r0.y), h0);
        fma8(accB, __int_as_float(r1.y), h1);
        fma8(accA, __int_as_float(r2.y), h2);
        fma8(accB, __int_as_float(r3.y), h3);
    }
    if (jb < end) {
        int endm1 = end - 1;       // >= jb >= 0 here
        int e0 = jb + g4, e1 = jb + 4 + g4, e2 = jb + 8 + g4, e3 = jb + 12 + g4;
        int2 r0 = t.recs[min(e0, endm1)];
        int2 r1 = t.recs[min(e1, endm1)];
        int2 r2 = t.recs[min(e2, endm1)];
        int2 r3 = t.recs[min(e3, endm1)];
        if (e0 < end) { uint4 h = ((const uint4*)(t.gsrc + (size_t)r0.x * 64))[l8]; fma8(accA, __int_as_float(r0.y), h); }
        if (e1 < end) { uint4 h = ((const uint4*)(t.gsrc + (size_t)r1.x * 64))[l8]; fma8(accB, __int_as_float(r1.y), h); }
        if (e2 < end) { uint4 h = ((const uint4*)(t.gsrc + (size_t)r2.x * 64))[l8]; fma8(accA, __int_as_float(r2.y), h); }
        if (e3 < end) { uint4 h = ((const uint4*)(t.gsrc + (size_t)r3.x * 64))[l8]; fma8(accB, __int_as_float(r3.y), h); }
    }
    float acc[8];
    #pragma unroll
    for (int m = 0; m < 8; ++m) acc[m] = accA[m] + accB[m];
    #pragma unroll
    for (int off = 8; off <= 16; off <<= 1)
        #pragma unroll
        for (int m = 0; m < 8; ++m)
            acc[m] += __shfl_xor(acc[m], off);

    // residual + bias + LayerNorm
    const float4* xi = (const float4*)(t.xin + (size_t)row * 64 + 8 * l8);
    const float4* bi = (const float4*)(t.bias + 8 * l8);
    float4 x0 = xi[0], x1 = xi[1];
    float4 bb0 = bi[0], bb1 = bi[1];
    float tv[8];
    tv[0] = x0.x + acc[0] + bb0.x; tv[1] = x0.y + acc[1] + bb0.y;
    tv[2] = x0.z + acc[2] + bb0.z; tv[3] = x0.w + acc[3] + bb0.w;
    tv[4] = x1.x + acc[4] + bb1.x; tv[5] = x1.y + acc[5] + bb1.y;
    tv[6] = x1.z + acc[6] + bb1.z; tv[7] = x1.w + acc[7] + bb1.w;

    float s = 0.f;
    #pragma unroll
    for (int m = 0; m < 8; ++m) s += tv[m];
    #pragma unroll
    for (int off = 1; off <= 4; off <<= 1) s += __shfl_xor(s, off);
    float mean = s * (1.0f / 64.0f);
    float q = 0.f;
    #pragma unroll
    for (int m = 0; m < 8; ++m) { float dv = tv[m] - mean; q += dv * dv; }
    #pragma unroll
    for (int off = 1; off <= 4; off <<= 1) q += __shfl_xor(q, off);
    float rs = rsqrtf(q * (1.0f / 64.0f) + EPS_LN);

    if (g4 == 0) {
        const float4* ga = (const float4*)(t.gamma + 8 * l8);
        const float4* be = (const float4*)(t.beta + 8 * l8);
        float4 g0 = ga[0], g1 = ga[1];
        float4 e0 = be[0], e1 = be[1];
        float4 y0, y1;
        y0.x = (tv[0] - mean) * rs * g0.x + e0.x;
        y0.y = (tv[1] - mean) * rs * g0.y + e0.y;
        y0.z = (tv[2] - mean) * rs * g0.z + e0.z;
        y0.w = (tv[3] - mean) * rs * g0.w + e0.w;
        y1.x = (tv[4] - mean) * rs * g1.x + e1.x;
        y1.y = (tv[5] - mean) * rs * g1.y + e1.y;
        y1.z = (tv[6] - mean) * rs * g1.z + e1.z;
        y1.w = (tv[7] - mean) * rs * g1.w + e1.w;
        float4* yo = (float4*)(t.yout + (size_t)row * 64 + 8 * l8);
        yo[0] = y0;
        yo[1] = y1;
    }
}

extern "C" void kernel_launch(void* const* d_in, const int* in_sizes, int n_in,
                              void* d_out, int out_size, void* d_ws, size_t ws_size,
                              hipStream_t stream)
{
    const float* user_emb = (const float*)d_in[0];
    const float* item_emb = (const float*)d_in[1];
    const int*   ui_src   = (const int*)d_in[2];
    const int*   ui_dst   = (const int*)d_in[3];
    const float* ui_val   = (const float*)d_in[4];
    const int*   soc_src  = (const int*)d_in[5];
    const int*   soc_dst  = (const int*)d_in[6];
    const float* soc_val  = (const float*)d_in[7];
    const float* W_ui     = (const float*)d_in[8];
    const float* b_ui     = (const float*)d_in[9];
    const float* W_soc    = (const float*)d_in[10];
    const float* b_soc    = (const float*)d_in[11];
    const float* ln_g     = (const float*)d_in[12];
    const float* ln_b     = (const float*)d_in[13];

    float* out     = (float*)d_out;
    float* out_ui  = out;                         // [3][NU][D]
    float* out_soc = out + (size_t)3 * NU * D;    // [3][NU][D]
    float* out_it  = out + (size_t)6 * NU * D;    // [NI][D]

    const int NBU = (NU + BROWS - 1) / BROWS;     // 196
    const int NBI = (NI + BROWS - 1) / BROWS;     // 391
    const int BLK_UI  = (E_UI  + CH - 1) / CH;    // 391
    const int BLK_SOC = (E_SOC + CH - 1) / CH;    // 196

    const int N1 = NBU * BLK_UI;    // 76636
    const int N2 = NBI * BLK_UI;    // 152881
    const int N3 = NBU * BLK_SOC;   // 38416
    const int SB1 = (N1 + 255) / 256, SB2 = (N2 + 255) / 256, SB3 = (N3 + 255) / 256;

    // ---- workspace carve (256B-aligned) ----
    char* p = (char*)d_ws;
    auto take = [&](size_t bytes) { char* r = p; p += (bytes + 255) & ~(size_t)255; return r; };
    int2* rec_us = (int2*)take((size_t)E_UI * 8);
    int2* rec_ud = (int2*)take((size_t)E_UI * 8);
    int2* rec_ss = (int2*)take((size_t)E_SOC * 8);
    int2* bin1 = (int2*)take((size_t)E_UI * 8);    // reused as twu after CSR build
    int2* bin2 = (int2*)take((size_t)E_UI * 8);
    int2* bin3 = (int2*)take((size_t)E_SOC * 8);
    int*  rp_us  = (int*)take((size_t)(NU + 1) * 4);
    int*  rp_ud  = (int*)take((size_t)(NI + 1) * 4);
    int*  rp_ss  = (int*)take((size_t)(NU + 1) * 4);
    int*  cnt1 = (int*)take((size_t)N1 * 4);
    int*  cnt2 = (int*)take((size_t)N2 * 4);
    int*  cnt3 = (int*)take((size_t)N3 * 4);
    int*  ofs1 = (int*)take((size_t)N1 * 4);
    int*  ofs2 = (int*)take((size_t)N2 * 4);
    int*  ofs3 = (int*)take((size_t)N3 * 4);
    int*  bs1 = (int*)take(1024 * 4);
    int*  bs2 = (int*)take(1024 * 4);
    int*  bs3 = (int*)take(1024 * 4);
    unsigned short* twi = (unsigned short*)take((size_t)NU * D * 2);  // u_cur @ W_ui
    unsigned short* tws = (unsigned short*)take((size_t)NU * D * 2);  // s_cur @ W_soc
    unsigned short* twu = (unsigned short*)bin1;                      // it_cur @ W_ui (NI rows)

    // ---- CSR build: 6 merged dispatches ----
    {
        CntT c1 { ui_src,  E_UI,  BLK_UI,  NBU, cnt1, 0 };
        CntT c2 { ui_dst,  E_UI,  BLK_UI,  NBI, cnt2, BLK_UI };
        CntT c3 { soc_src, E_SOC, BLK_SOC, NBU, cnt3, 2 * BLK_UI };
        bin_count3<<<2 * BLK_UI + BLK_SOC, 256, 0, stream>>>(c1, c2, c3);
    }
    {
        ScanT s1 { cnt1, N1, bs1, ofs1, 0 };
        ScanT s2 { cnt2, N2, bs2, ofs2, SB1 };
        ScanT s3 { cnt3, N3, bs3, ofs3, SB1 + SB2 };
        scan_partial3<<<SB1 + SB2 + SB3, 256, 0, stream>>>(s1, s2, s3);
        scan_bsums3<<<3, 1024, 0, stream>>>(s1, s2, s3);
        scan_out3<<<SB1 + SB2 + SB3, 256, 0, stream>>>(s1, s2, s3);
    }
    {
        ScatT c1 { ui_src,  ui_dst,  ui_val,  E_UI,  BLK_UI,  ofs1, NBU, bin1, 0 };
        ScatT c2 { ui_dst,  ui_src,  ui_val,  E_UI,  BLK_UI,  ofs2, NBI, bin2, BLK_UI };
        ScatT c3 { soc_src, soc_dst, soc_val, E_SOC, BLK_SOC, ofs3, NBU, bin3, 2 * BLK_UI };
        bin_scatter3<<<2 * BLK_UI + BLK_SOC, 256, 0, stream>>>(c1, c2, c3);
    }
    {
        FineT f1 { bin1, ofs1, BLK_UI,  NBU, E_UI,  NU, rp_us, rec_us, 0 };
        FineT f2 { bin2, ofs2, BLK_UI,  NBI, E_UI,  NI, rp_ud, rec_ud, NBU };
        FineT f3 { bin3, ofs3, BLK_SOC, NBU, E_SOC, NU, rp_ss, rec_ss, NBU + NBI };
        fine_scatter3<<<NBU + NBI + NBU, 512, 0, stream>>>(f1, f2, f3);
    }

    const float* u0 = user_emb;
    float* u1 = out_ui + (size_t)NU * D;
    float* u2 = out_ui + (size_t)2 * NU * D;
    const float* s0 = user_emb;
    float* s1 = out_soc + (size_t)NU * D;
    float* s2 = out_soc + (size_t)2 * NU * D;

    int ublocks8 = (NU + 7) / 8;   // 12500  (8 rows per 256-thread block)
    int iblocks8 = (NI + 7) / 8;   // 25000
    int agrid    = iblocks8 + 2 * ublocks8;

    const int TB_I = 1040, TB_U = 520, TB_S = 520;
    int tgrid = TB_I + TB_U + TB_S;
    const int TIL_I = NI / 16, TIL_U = NU / 16;   // 12500, 6250

    // ---- layer 0 (btab3 runs right before spmmln3; tb folds copy0) ----
    {
        TaskT ta { item_emb, twu, W_ui + 0 * 4096, TIL_I, 0, TB_I, nullptr, nullptr };
        TaskT tb { u0,       twi, W_ui + 0 * 4096, TIL_U, TB_I, TB_U, out_ui, out_soc };
        TaskT tc { u0,       tws, W_soc + 0 * 4096, TIL_U, TB_I + TB_U, TB_S, nullptr, nullptr };
        btab3<<<tgrid, 256, 0, stream>>>(ta, tb, tc);
    }
    {
        TaskS si { twi, item_emb, out_it, rp_ud, rec_ud, b_ui + 0 * 64,
                   ln_g + 1 * 64, ln_b + 1 * 64, NI, 0 };
        TaskS su { twu, u0, u1, rp_us, rec_us, b_ui + 0 * 64,
                   ln_g + 0 * 64, ln_b + 0 * 64, NU, iblocks8 };
        TaskS ss { tws, s0, s1, rp_ss, rec_ss, b_soc + 0 * 64,
                   ln_g + 0 * 64, ln_b + 0 * 64, NU, iblocks8 + ublocks8 };
        spmmln3<<<agrid, 256, 0, stream>>>(si, su, ss);
    }

    // ---- layer 1 ----
    {
        TaskT ta { out_it, twu, W_ui + 1 * 4096, TIL_I, 0, TB_I, nullptr, nullptr };
        TaskT tb { u1,     twi, W_ui + 1 * 4096, TIL_U, TB_I, TB_U, nullptr, nullptr };
        TaskT tc { s1,     tws, W_soc + 1 * 4096, TIL_U, TB_I + TB_U, TB_S, nullptr, nullptr };
        btab3<<<tgrid, 256, 0, stream>>>(ta, tb, tc);
    }
    {
        TaskS si { twi, out_it, out_it, rp_ud, rec_ud, b_ui + 1 * 64,
                   ln_g + 3 * 64, ln_b + 3 * 64, NI, 0 };
        TaskS su { twu, u1, u2, rp_us, rec_us, b_ui + 1 * 64,
                   ln_g + 2 * 64, ln_b + 2 * 64, NU, iblocks8 };
        TaskS ss { tws, s1, s2, rp_ss, rec_ss, b_soc + 1 * 64,
                   ln_g + 2 * 64, ln_b + 2 * 64, NU, iblocks8 + ublocks8 };
        spmmln3<<<agrid, 256, 0, stream>>>(si, su, ss);
    }
}